// Round 20
// baseline (62.079 us; speedup 1.0000x reference)
//
#include <hip/hip_runtime.h>
#include <hip/hip_bf16.h>
#include <math.h>

#define NROWS 131072
#define NCODE 512
#define DIM 128
#define ESCALE 256.0f       // emb * 2^8 into fp8 (raw |e|~0.001 underflows e4m3)
#define DESCALE 0.0078125f  // 2/256: sv = e2 - 2*dot = e2 - DESCALE*acc

typedef long long llong;
typedef __attribute__((ext_vector_type(16))) float f32x16;

__device__ inline llong mk_ll(int lo, int hi) {
    return ((llong)(unsigned long long)(unsigned)hi << 32) | (unsigned)lo;
}

// Stuff the 9-bit code index into the low mantissa bits of the score.
// Perturbs sv by < ~1e-6 (fp8 score error budget is ~5e-4). Min over keys ==
// min over scores; index rides inside the value through fmin trees & shuffles.
__device__ inline float kstuff(float sv, int code) {
    return __uint_as_float((__float_as_uint(sv) & 0xFFFFFE00u) | (unsigned)code);
}

// Fused prep: one block per 32-code M-tile.
//  - afp[(mt*4+q)*64 + lane]: fp8 A-fragments of emb*256 in lane order
//  - e2p[mt*32 + g*16 + r]:  ||e||^2 (fp32 exact) in D-fragment order
__global__ __launch_bounds__(256) void prep_pack8(const float* __restrict__ emb,
        int4* __restrict__ afp, float* __restrict__ e2p) {
    __shared__ float part[32][8];
    const int tid = threadIdx.x;
    const int mt = blockIdx.x;
    const int lane = tid & 63, q = tid >> 6;        // q in 0..3
    const int c5 = lane & 31, g = lane >> 5;
    const int code = mt * 32 + c5;
    const float* src = emb + (size_t)code * DIM;

    int w[4];
    float ss = 0.f;
    #pragma unroll
    for (int h = 0; h < 2; ++h) {
        int d0 = (2 * q + h) * 16 + g * 8;
        float4 v0 = *reinterpret_cast<const float4*>(src + d0);
        float4 v1 = *reinterpret_cast<const float4*>(src + d0 + 4);
        ss = fmaf(v0.x, v0.x, ss); ss = fmaf(v0.y, v0.y, ss);
        ss = fmaf(v0.z, v0.z, ss); ss = fmaf(v0.w, v0.w, ss);
        ss = fmaf(v1.x, v1.x, ss); ss = fmaf(v1.y, v1.y, ss);
        ss = fmaf(v1.z, v1.z, ss); ss = fmaf(v1.w, v1.w, ss);
        int lo = __builtin_amdgcn_cvt_pk_fp8_f32(v0.x * ESCALE, v0.y * ESCALE, 0, false);
        lo = __builtin_amdgcn_cvt_pk_fp8_f32(v0.z * ESCALE, v0.w * ESCALE, lo, true);
        int hi = __builtin_amdgcn_cvt_pk_fp8_f32(v1.x * ESCALE, v1.y * ESCALE, 0, false);
        hi = __builtin_amdgcn_cvt_pk_fp8_f32(v1.z * ESCALE, v1.w * ESCALE, hi, true);
        w[2 * h] = lo; w[2 * h + 1] = hi;
    }
    afp[(mt * 4 + q) * 64 + lane] = make_int4(w[0], w[1], w[2], w[3]);
    part[c5][q * 2 + g] = ss;
    __syncthreads();
    if (tid < 32) {
        float s = 0.f;
        #pragma unroll
        for (int j = 0; j < 8; ++j) s += part[tid][j];   // fixed order: deterministic
        int g2 = (tid >> 2) & 1;
        int r = (tid & 3) | ((tid >> 3) << 2);
        e2p[mt * 32 + g2 * 16 + r] = s;
    }
}

// De-convoyed argmin: block = 2 waves x 128 rows; wave = 64 rows x ALL 512
// codes. ONE barrier (after ingest); after it every wave is fully autonomous —
// no cross-wave merge, no s_fidx, no post-loop syncthreads. Waves retire and
// start their out0 writes independently, smoothing the chip-wide HBM
// read/write mix (six convoy-phased structures all converged to ~43 µs at
// 2.4 of 6.3 TB/s sustained). A from L2-hot afp; t-loop unroll 1; min-tree.
__global__ __launch_bounds__(128, 4) void vq_argmin(
        const float* __restrict__ x, const float* __restrict__ emb,
        const int4* __restrict__ afp, const float* __restrict__ e2p,
        int* __restrict__ idxg,
        float* __restrict__ out0, float* __restrict__ out1, float* __restrict__ out2) {
    __shared__ unsigned char xs8[128][DIM];  // fp8 rows, byte off ^= ((row&15)<<3)
    __shared__ float x2s[128];

    const int tid = threadIdx.x;
    const int lane = tid & 63, l31 = lane & 31, g = lane >> 5;
    const long row0 = (long)blockIdx.x * 128;

    // ---- coalesced ingest: per it, each 32-lane group covers one full row ----
    {
        const float4* xg = reinterpret_cast<const float4*>(x + row0 * DIM);
        #pragma unroll
        for (int it = 0; it < 32; ++it) {
            int i = it * 128 + tid;
            float4 v = xg[i];
            int r = i >> 5, c = i & 31;
            float s = v.x * v.x + v.y * v.y + v.z * v.z + v.w * v.w;
            s += __shfl_xor(s, 1);  s += __shfl_xor(s, 2);
            s += __shfl_xor(s, 4);  s += __shfl_xor(s, 8);
            s += __shfl_xor(s, 16);
            if ((tid & 31) == 0) x2s[r] = s;
            int w = __builtin_amdgcn_cvt_pk_fp8_f32(v.x, v.y, 0, false);
            w = __builtin_amdgcn_cvt_pk_fp8_f32(v.z, v.w, w, true);
            int off = (c * 4) ^ ((r & 15) << 3);
            *reinterpret_cast<int*>(&xs8[r][off]) = w;
        }
    }
    __syncthreads();   // the ONLY barrier

    const int wv = tid >> 6;               // 0..1
    const int r0 = wv * 64 + l31;          // row tile 0
    const int r1 = wv * 64 + 32 + l31;     // row tile 1

    // ---- B-fragments from LDS: 2 row-tiles x 8 llong = 32 VGPR ----
    #define RB(RR, K) *reinterpret_cast<const llong*>(&xs8[RR][((K) * 16 + g * 8) ^ (((RR) & 15) << 3)])
    const llong b0 = RB(r0, 0), b1 = RB(r0, 1), b2 = RB(r0, 2), b3 = RB(r0, 3);
    const llong b4 = RB(r0, 4), b5 = RB(r0, 5), b6 = RB(r0, 6), b7 = RB(r0, 7);
    const llong c0 = RB(r1, 0), c1 = RB(r1, 1), c2 = RB(r1, 2), c3 = RB(r1, 3);
    const llong c4 = RB(r1, 4), c5 = RB(r1, 5), c6 = RB(r1, 6), c7 = RB(r1, 7);
    #undef RB

    float m1a = 1e30f, m1b = 1e30f;   // index-stuffed running min keys

    // ---- 16 M-tiles (ALL 512 codes); 4 A-loads -> 16 MFMA per tile ----
    #pragma unroll 1
    for (int mt = 0; mt < 16; ++mt) {
        const int4* ap = afp + mt * 256 + lane;
        int4 A0 = ap[0];
        int4 A1 = ap[64];
        int4 A2 = ap[128];
        int4 A3 = ap[192];
        f32x16 acc0 = {}, acc1 = {};
        acc0 = __builtin_amdgcn_mfma_f32_32x32x16_fp8_fp8(mk_ll(A0.x, A0.y), b0, acc0, 0, 0, 0);
        acc1 = __builtin_amdgcn_mfma_f32_32x32x16_fp8_fp8(mk_ll(A0.x, A0.y), c0, acc1, 0, 0, 0);
        acc0 = __builtin_amdgcn_mfma_f32_32x32x16_fp8_fp8(mk_ll(A0.z, A0.w), b1, acc0, 0, 0, 0);
        acc1 = __builtin_amdgcn_mfma_f32_32x32x16_fp8_fp8(mk_ll(A0.z, A0.w), c1, acc1, 0, 0, 0);
        acc0 = __builtin_amdgcn_mfma_f32_32x32x16_fp8_fp8(mk_ll(A1.x, A1.y), b2, acc0, 0, 0, 0);
        acc1 = __builtin_amdgcn_mfma_f32_32x32x16_fp8_fp8(mk_ll(A1.x, A1.y), c2, acc1, 0, 0, 0);
        acc0 = __builtin_amdgcn_mfma_f32_32x32x16_fp8_fp8(mk_ll(A1.z, A1.w), b3, acc0, 0, 0, 0);
        acc1 = __builtin_amdgcn_mfma_f32_32x32x16_fp8_fp8(mk_ll(A1.z, A1.w), c3, acc1, 0, 0, 0);
        acc0 = __builtin_amdgcn_mfma_f32_32x32x16_fp8_fp8(mk_ll(A2.x, A2.y), b4, acc0, 0, 0, 0);
        acc1 = __builtin_amdgcn_mfma_f32_32x32x16_fp8_fp8(mk_ll(A2.x, A2.y), c4, acc1, 0, 0, 0);
        acc0 = __builtin_amdgcn_mfma_f32_32x32x16_fp8_fp8(mk_ll(A2.z, A2.w), b5, acc0, 0, 0, 0);
        acc1 = __builtin_amdgcn_mfma_f32_32x32x16_fp8_fp8(mk_ll(A2.z, A2.w), c5, acc1, 0, 0, 0);
        acc0 = __builtin_amdgcn_mfma_f32_32x32x16_fp8_fp8(mk_ll(A3.x, A3.y), b6, acc0, 0, 0, 0);
        acc1 = __builtin_amdgcn_mfma_f32_32x32x16_fp8_fp8(mk_ll(A3.x, A3.y), c6, acc1, 0, 0, 0);
        acc0 = __builtin_amdgcn_mfma_f32_32x32x16_fp8_fp8(mk_ll(A3.z, A3.w), b7, acc0, 0, 0, 0);
        acc1 = __builtin_amdgcn_mfma_f32_32x32x16_fp8_fp8(mk_ll(A3.z, A3.w), c7, acc1, 0, 0, 0);

        const float4* ev = reinterpret_cast<const float4*>(e2p + mt * 32 + g * 16);
        const int base = mt * 32 + 4 * g;
        float4 ea = ev[0], eb = ev[1], ec = ev[2], ed = ev[3];
        float earr[16] = {ea.x, ea.y, ea.z, ea.w, eb.x, eb.y, eb.z, eb.w,
                          ec.x, ec.y, ec.z, ec.w, ed.x, ed.y, ed.z, ed.w};
        float k0[16], k1[16];
        #pragma unroll
        for (int r = 0; r < 16; ++r) {
            int code = base + (r & 3) + 8 * (r >> 2);
            k0[r] = kstuff(earr[r] - DESCALE * acc0[r], code);
            k1[r] = kstuff(earr[r] - DESCALE * acc1[r], code);
        }
        #pragma unroll
        for (int s = 8; s > 0; s >>= 1)
            #pragma unroll
            for (int r = 0; r < s; ++r) {
                k0[r] = fminf(k0[r], k0[r + s]);
                k1[r] = fminf(k1[r], k1[r + s]);
            }
        m1a = fminf(m1a, k0[0]);
        m1b = fminf(m1b, k1[0]);
    }

    // g-half merge: both lanes (l, l+32) then hold the rows' final keys
    m1a = fminf(m1a, __shfl_xor(m1a, 32));
    m1b = fminf(m1b, __shfl_xor(m1b, 32));
    const unsigned ka = __float_as_uint(m1a), kbb = __float_as_uint(m1b);
    const int idxa = (int)(ka & 0x1FFu), idxb = (int)(kbb & 0x1FFu);
    const float sva = __uint_as_float(ka & 0xFFFFFE00u);
    const float svb = __uint_as_float(kbb & 0xFFFFFE00u);

    if (lane < 32) {
        long rowA = row0 + r0;
        long rowB = row0 + r1;
        idxg[rowA] = idxa;
        idxg[rowB] = idxb;
        float oa = x2s[r0] + sva;   // ||x||^2 + (||e||^2 - 2 x.e); err ~1e-3 << 4.24
        float ob = x2s[r1] + svb;
        out1[rowA] = oa; out2[rowA] = oa;
        out1[rowB] = ob; out2[rowB] = ob;
    }

    // ---- gather: wave writes its 64 rows, idx broadcast via shfl (no LDS,
    // no barrier — starts the moment THIS wave finishes its t-loop) ----
    {
        const float4* e4 = reinterpret_cast<const float4*>(emb);
        float4* o4 = reinterpret_cast<float4*>(out0) + (row0 + wv * 64) * 32;
        #pragma unroll 4
        for (int rx = 0; rx < 32; rx += 2) {
            int ca = __shfl(idxa, rx);
            int cb = __shfl(idxa, rx + 1);
            int c = g ? cb : ca;
            o4[(rx + g) * 32 + l31] = e4[c * 32 + l31];
        }
        #pragma unroll 4
        for (int rx = 0; rx < 32; rx += 2) {
            int ca = __shfl(idxb, rx);
            int cb = __shfl(idxb, rx + 1);
            int c = g ? cb : ca;
            o4[(32 + rx + g) * 32 + l31] = e4[c * 32 + l31];
        }
    }
}

// Stage A: 64 blocks build LDS partial histograms (2048 rows each) — LDS
// atomics only, no global atomics anywhere.
__global__ __launch_bounds__(256) void hist_part(const int* __restrict__ idxg,
        int* __restrict__ partial) {
    __shared__ int h[NCODE];
    const int tid = threadIdx.x, b = blockIdx.x;
    h[tid] = 0; h[tid + 256] = 0;
    __syncthreads();
    const int4* i4 = reinterpret_cast<const int4*>(idxg + b * 2048);
    #pragma unroll
    for (int k = 0; k < 2; ++k) {
        int4 v = i4[k * 256 + tid];
        atomicAdd(&h[v.x], 1); atomicAdd(&h[v.y], 1);
        atomicAdd(&h[v.z], 1); atomicAdd(&h[v.w], 1);
    }
    __syncthreads();
    partial[b * NCODE + tid] = h[tid];
    partial[b * NCODE + 256 + tid] = h[tid + 256];
}

// Stage B: sum 64 partials per bin, entropy reduce.
__global__ void entropy_kernel(const int* __restrict__ partial,
        float* __restrict__ oent) {
    __shared__ float red[8];
    int tid = threadIdx.x;  // 512 threads
    int c = 0;
    #pragma unroll
    for (int b = 0; b < 64; ++b) c += partial[b * NCODE + tid];
    float p = (float)c * (1.0f / 131072.0f);
    float t = (p > 0.f) ? (-p * logf(p)) : 0.f;
    #pragma unroll
    for (int off = 32; off > 0; off >>= 1) t += __shfl_down(t, off);
    if ((tid & 63) == 0) red[tid >> 6] = t;
    __syncthreads();
    if (tid == 0) {
        float s = 0.f;
        #pragma unroll
        for (int i = 0; i < 8; ++i) s += red[i];
        *oent = s;
    }
}

extern "C" void kernel_launch(void* const* d_in, const int* in_sizes, int n_in,
                              void* d_out, int out_size, void* d_ws, size_t ws_size,
                              hipStream_t stream) {
    const float* x   = (const float*)d_in[0];
    const float* emb = (const float*)d_in[1];
    float* out  = (float*)d_out;
    float* out0 = out;
    float* out1 = out0 + (size_t)NROWS * DIM;
    float* out2 = out1 + NROWS;
    float* oent = out2 + NROWS;

    float* e2p = (float*)d_ws;                                    // 2 KB
    int4*  afp = (int4*)((char*)d_ws + 4096);                     // 64 KB
    int*   idxg = (int*)((char*)d_ws + 4096 + 65536);             // 512 KB
    int*   partial = (int*)((char*)d_ws + 4096 + 65536 + 524288); // 128 KB

    prep_pack8<<<16, 256, 0, stream>>>(emb, afp, e2p);
    vq_argmin<<<NROWS / 128, 128, 0, stream>>>(x, emb, afp, e2p, idxg, out0, out1, out2);
    hist_part<<<64, 256, 0, stream>>>(idxg, partial);
    entropy_kernel<<<1, NCODE, 0, stream>>>(partial, oent);
}

// Round 21
// 47.263 us; speedup vs baseline: 1.3135x; 1.3135x over previous
//
#include <hip/hip_runtime.h>
#include <hip/hip_bf16.h>
#include <math.h>

#define NROWS 131072
#define NCODE 512
#define DIM 128
#define ESCALE 256.0f       // emb * 2^8 into fp8 (raw |e|~0.001 underflows e4m3)
#define DESCALE 0.0078125f  // 2/256: sv = e2 - 2*dot = e2 - DESCALE*acc

typedef long long llong;
typedef __attribute__((ext_vector_type(16))) float f32x16;

__device__ inline llong mk_ll(int lo, int hi) {
    return ((llong)(unsigned long long)(unsigned)hi << 32) | (unsigned)lo;
}

// Stuff the 9-bit code index into the low mantissa bits of the score.
// Perturbs sv by < 2^(exp-14) ~ 1e-6 (score err budget is ~5e-4).
// Min over keys == min over scores; index travels inside the value.
__device__ inline float kstuff(float sv, int code) {
    return __uint_as_float((__float_as_uint(sv) & 0xFFFFFE00u) | (unsigned)code);
}

// Fused prep: one block per 32-code M-tile.
//  - afp[(mt*4+q)*64 + lane]: fp8 A-fragments of emb*256 in lane order
//  - e2p[mt*32 + g*16 + r]:  ||e||^2 (fp32 exact) in D-fragment order
__global__ __launch_bounds__(256) void prep_pack8(const float* __restrict__ emb,
        int4* __restrict__ afp, float* __restrict__ e2p) {
    __shared__ float part[32][8];
    const int tid = threadIdx.x;
    const int mt = blockIdx.x;
    const int lane = tid & 63, q = tid >> 6;        // q in 0..3
    const int c5 = lane & 31, g = lane >> 5;
    const int code = mt * 32 + c5;
    const float* src = emb + (size_t)code * DIM;

    int w[4];
    float ss = 0.f;
    #pragma unroll
    for (int h = 0; h < 2; ++h) {
        int d0 = (2 * q + h) * 16 + g * 8;
        float4 v0 = *reinterpret_cast<const float4*>(src + d0);
        float4 v1 = *reinterpret_cast<const float4*>(src + d0 + 4);
        ss = fmaf(v0.x, v0.x, ss); ss = fmaf(v0.y, v0.y, ss);
        ss = fmaf(v0.z, v0.z, ss); ss = fmaf(v0.w, v0.w, ss);
        ss = fmaf(v1.x, v1.x, ss); ss = fmaf(v1.y, v1.y, ss);
        ss = fmaf(v1.z, v1.z, ss); ss = fmaf(v1.w, v1.w, ss);
        int lo = __builtin_amdgcn_cvt_pk_fp8_f32(v0.x * ESCALE, v0.y * ESCALE, 0, false);
        lo = __builtin_amdgcn_cvt_pk_fp8_f32(v0.z * ESCALE, v0.w * ESCALE, lo, true);
        int hi = __builtin_amdgcn_cvt_pk_fp8_f32(v1.x * ESCALE, v1.y * ESCALE, 0, false);
        hi = __builtin_amdgcn_cvt_pk_fp8_f32(v1.z * ESCALE, v1.w * ESCALE, hi, true);
        w[2 * h] = lo; w[2 * h + 1] = hi;
    }
    afp[(mt * 4 + q) * 64 + lane] = make_int4(w[0], w[1], w[2], w[3]);
    part[c5][q * 2 + g] = ss;
    __syncthreads();
    if (tid < 32) {
        float s = 0.f;
        #pragma unroll
        for (int j = 0; j < 8; ++j) s += part[tid][j];   // fixed order: deterministic
        int g2 = (tid >> 2) & 1;
        int r = (tid & 3) | ((tid >> 3) << 2);
        e2p[mt * 32 + g2 * 16 + r] = s;
    }
}

// Block = 4 waves = 2 row-groups x 2 code-halves; 128 rows x 512 codes.
// Wave = 64 rows x 256 codes. Argmin via index-stuffed fminf TREE (no serial
// cmp/cndmask chain). t-loop unroll 1 (r13/r15: forced unrolling regresses);
// no global atomics (r13/r14: ~40 µs cost). This is the empirical optimum
// after 7 orthogonal structural probes (r12..r20) — all converge to ~43 µs;
// binder is distributed memory latency, not any single pipe.
__global__ __launch_bounds__(256, 4) void vq_argmin(
        const float* __restrict__ x, const float* __restrict__ emb,
        const int4* __restrict__ afp, const float* __restrict__ e2p,
        int* __restrict__ idxg,
        float* __restrict__ out0, float* __restrict__ out1, float* __restrict__ out2) {
    __shared__ unsigned char xs8[128][DIM];  // fp8 rows, byte off ^= ((row&15)<<3)
    __shared__ float x2s[128];
    __shared__ float s_m[2][2][64];
    __shared__ int   s_fidx[2][64];

    const int tid = threadIdx.x;
    const int lane = tid & 63, l31 = lane & 31, g = lane >> 5;
    const long row0 = (long)blockIdx.x * 128;

    // ---- coalesced ingest: per it, each 32-lane group covers one full row ----
    {
        const float4* xg = reinterpret_cast<const float4*>(x + row0 * DIM);
        #pragma unroll
        for (int it = 0; it < 16; ++it) {
            float4 v = xg[it * 256 + tid];
            int r = it * 8 + (tid >> 5), c = tid & 31;
            float s = v.x * v.x + v.y * v.y + v.z * v.z + v.w * v.w;
            s += __shfl_xor(s, 1);  s += __shfl_xor(s, 2);
            s += __shfl_xor(s, 4);  s += __shfl_xor(s, 8);
            s += __shfl_xor(s, 16);
            if ((tid & 31) == 0) x2s[r] = s;
            int w = __builtin_amdgcn_cvt_pk_fp8_f32(v.x, v.y, 0, false);
            w = __builtin_amdgcn_cvt_pk_fp8_f32(v.z, v.w, w, true);
            int off = (c * 4) ^ ((r & 15) << 3);
            *reinterpret_cast<int*>(&xs8[r][off]) = w;
        }
    }
    __syncthreads();

    const int wv = tid >> 6, rg = wv >> 1, ch = wv & 1;
    const int r0 = rg * 64 + l31;          // row tile 0
    const int r1 = rg * 64 + 32 + l31;     // row tile 1

    // ---- B-fragments from LDS: 2 row-tiles x 8 llong = 32 VGPR ----
    #define RB(RR, K) *reinterpret_cast<const llong*>(&xs8[RR][((K) * 16 + g * 8) ^ (((RR) & 15) << 3)])
    const llong b0 = RB(r0, 0), b1 = RB(r0, 1), b2 = RB(r0, 2), b3 = RB(r0, 3);
    const llong b4 = RB(r0, 4), b5 = RB(r0, 5), b6 = RB(r0, 6), b7 = RB(r0, 7);
    const llong c0 = RB(r1, 0), c1 = RB(r1, 1), c2 = RB(r1, 2), c3 = RB(r1, 3);
    const llong c4 = RB(r1, 4), c5 = RB(r1, 5), c6 = RB(r1, 6), c7 = RB(r1, 7);
    #undef RB

    float m1a = 1e30f, m1b = 1e30f;   // index-stuffed running min keys

    // ---- 8 M-tiles (codes ch*256 .. +256); 4 A-loads -> 16 MFMA per tile ----
    #pragma unroll 1
    for (int t = 0; t < 8; ++t) {
        const int mt = ch * 8 + t;
        const int4* ap = afp + mt * 256 + lane;
        int4 A0 = ap[0];
        int4 A1 = ap[64];
        int4 A2 = ap[128];
        int4 A3 = ap[192];
        f32x16 acc0 = {}, acc1 = {};
        acc0 = __builtin_amdgcn_mfma_f32_32x32x16_fp8_fp8(mk_ll(A0.x, A0.y), b0, acc0, 0, 0, 0);
        acc1 = __builtin_amdgcn_mfma_f32_32x32x16_fp8_fp8(mk_ll(A0.x, A0.y), c0, acc1, 0, 0, 0);
        acc0 = __builtin_amdgcn_mfma_f32_32x32x16_fp8_fp8(mk_ll(A0.z, A0.w), b1, acc0, 0, 0, 0);
        acc1 = __builtin_amdgcn_mfma_f32_32x32x16_fp8_fp8(mk_ll(A0.z, A0.w), c1, acc1, 0, 0, 0);
        acc0 = __builtin_amdgcn_mfma_f32_32x32x16_fp8_fp8(mk_ll(A1.x, A1.y), b2, acc0, 0, 0, 0);
        acc1 = __builtin_amdgcn_mfma_f32_32x32x16_fp8_fp8(mk_ll(A1.x, A1.y), c2, acc1, 0, 0, 0);
        acc0 = __builtin_amdgcn_mfma_f32_32x32x16_fp8_fp8(mk_ll(A1.z, A1.w), b3, acc0, 0, 0, 0);
        acc1 = __builtin_amdgcn_mfma_f32_32x32x16_fp8_fp8(mk_ll(A1.z, A1.w), c3, acc1, 0, 0, 0);
        acc0 = __builtin_amdgcn_mfma_f32_32x32x16_fp8_fp8(mk_ll(A2.x, A2.y), b4, acc0, 0, 0, 0);
        acc1 = __builtin_amdgcn_mfma_f32_32x32x16_fp8_fp8(mk_ll(A2.x, A2.y), c4, acc1, 0, 0, 0);
        acc0 = __builtin_amdgcn_mfma_f32_32x32x16_fp8_fp8(mk_ll(A2.z, A2.w), b5, acc0, 0, 0, 0);
        acc1 = __builtin_amdgcn_mfma_f32_32x32x16_fp8_fp8(mk_ll(A2.z, A2.w), c5, acc1, 0, 0, 0);
        acc0 = __builtin_amdgcn_mfma_f32_32x32x16_fp8_fp8(mk_ll(A3.x, A3.y), b6, acc0, 0, 0, 0);
        acc1 = __builtin_amdgcn_mfma_f32_32x32x16_fp8_fp8(mk_ll(A3.x, A3.y), c6, acc1, 0, 0, 0);
        acc0 = __builtin_amdgcn_mfma_f32_32x32x16_fp8_fp8(mk_ll(A3.z, A3.w), b7, acc0, 0, 0, 0);
        acc1 = __builtin_amdgcn_mfma_f32_32x32x16_fp8_fp8(mk_ll(A3.z, A3.w), c7, acc1, 0, 0, 0);

        const float4* ev = reinterpret_cast<const float4*>(e2p + mt * 32 + g * 16);
        const int base = mt * 32 + 4 * g;
        float4 ea = ev[0], eb = ev[1], ec = ev[2], ed = ev[3];
        float earr[16] = {ea.x, ea.y, ea.z, ea.w, eb.x, eb.y, eb.z, eb.w,
                          ec.x, ec.y, ec.z, ec.w, ed.x, ed.y, ed.z, ed.w};
        float k0[16], k1[16];
        #pragma unroll
        for (int r = 0; r < 16; ++r) {
            int code = base + (r & 3) + 8 * (r >> 2);
            k0[r] = kstuff(earr[r] - DESCALE * acc0[r], code);
            k1[r] = kstuff(earr[r] - DESCALE * acc1[r], code);
        }
        // parallel min tree (compiler fuses to v_min3_f32); depth 4, static idx
        #pragma unroll
        for (int s = 8; s > 0; s >>= 1)
            #pragma unroll
            for (int r = 0; r < s; ++r) {
                k0[r] = fminf(k0[r], k0[r + s]);
                k1[r] = fminf(k1[r], k1[r + s]);
            }
        m1a = fminf(m1a, k0[0]);
        m1b = fminf(m1b, k1[0]);
    }

    // merge the two g-halves (same row on lane and lane^32) — index rides along
    m1a = fminf(m1a, __shfl_xor(m1a, 32));
    m1b = fminf(m1b, __shfl_xor(m1b, 32));
    if (lane < 32) {
        s_m[rg][ch][l31] = m1a;
        s_m[rg][ch][32 + l31] = m1b;
    }
    __syncthreads();

    // ---- merge code-halves; write idx/out1/out2 (128 rows by first 2 waves) ----
    if (tid < 128) {
        int rgx = tid >> 6, lr = tid & 63;
        float m1f = fminf(s_m[rgx][0][lr], s_m[rgx][1][lr]);
        unsigned kb = __float_as_uint(m1f);
        int i1f = (int)(kb & 0x1FFu);
        float sv = __uint_as_float(kb & 0xFFFFFE00u);   // de-stuffed score
        long row = row0 + tid;
        idxg[row] = i1f;
        s_fidx[rgx][lr] = i1f;
        float o = x2s[tid] + sv;   // ||x||^2 + (||e||^2 - 2 x.e); err ~1e-3 << 4.24
        out1[row] = o;
        out2[row] = o;
    }
    __syncthreads();

    // ---- fused gather: each wave writes 32 rows (2 rows/iter, half-wave each) ----
    {
        const float4* e4 = reinterpret_cast<const float4*>(emb);
        float4* o4 = reinterpret_cast<float4*>(out0);
        const int rb = wv * 32;
        #pragma unroll 4
        for (int rx = 0; rx < 32; rx += 2) {
            int lr = rb + rx + g;                 // local row in [0,128)
            int c = s_fidx[lr >> 6][lr & 63];
            o4[(row0 + lr) * 32 + l31] = e4[c * 32 + l31];
        }
    }
}

// Stage A: 64 blocks build LDS partial histograms (2048 rows each) — LDS
// atomics only, no global atomics anywhere.
__global__ __launch_bounds__(256) void hist_part(const int* __restrict__ idxg,
        int* __restrict__ partial) {
    __shared__ int h[NCODE];
    const int tid = threadIdx.x, b = blockIdx.x;
    h[tid] = 0; h[tid + 256] = 0;
    __syncthreads();
    const int4* i4 = reinterpret_cast<const int4*>(idxg + b * 2048);
    #pragma unroll
    for (int k = 0; k < 2; ++k) {
        int4 v = i4[k * 256 + tid];
        atomicAdd(&h[v.x], 1); atomicAdd(&h[v.y], 1);
        atomicAdd(&h[v.z], 1); atomicAdd(&h[v.w], 1);
    }
    __syncthreads();
    partial[b * NCODE + tid] = h[tid];
    partial[b * NCODE + 256 + tid] = h[tid + 256];
}

// Stage B: sum 64 partials per bin, entropy reduce.
__global__ void entropy_kernel(const int* __restrict__ partial,
        float* __restrict__ oent) {
    __shared__ float red[8];
    int tid = threadIdx.x;  // 512 threads
    int c = 0;
    #pragma unroll
    for (int b = 0; b < 64; ++b) c += partial[b * NCODE + tid];
    float p = (float)c * (1.0f / 131072.0f);
    float t = (p > 0.f) ? (-p * logf(p)) : 0.f;
    #pragma unroll
    for (int off = 32; off > 0; off >>= 1) t += __shfl_down(t, off);
    if ((tid & 63) == 0) red[tid >> 6] = t;
    __syncthreads();
    if (tid == 0) {
        float s = 0.f;
        #pragma unroll
        for (int i = 0; i < 8; ++i) s += red[i];
        *oent = s;
    }
}

extern "C" void kernel_launch(void* const* d_in, const int* in_sizes, int n_in,
                              void* d_out, int out_size, void* d_ws, size_t ws_size,
                              hipStream_t stream) {
    const float* x   = (const float*)d_in[0];
    const float* emb = (const float*)d_in[1];
    float* out  = (float*)d_out;
    float* out0 = out;
    float* out1 = out0 + (size_t)NROWS * DIM;
    float* out2 = out1 + NROWS;
    float* oent = out2 + NROWS;

    float* e2p = (float*)d_ws;                                    // 2 KB
    int4*  afp = (int4*)((char*)d_ws + 4096);                     // 64 KB
    int*   idxg = (int*)((char*)d_ws + 4096 + 65536);             // 512 KB
    int*   partial = (int*)((char*)d_ws + 4096 + 65536 + 524288); // 128 KB

    prep_pack8<<<16, 256, 0, stream>>>(emb, afp, e2p);
    vq_argmin<<<NROWS / 128, 256, 0, stream>>>(x, emb, afp, e2p, idxg, out0, out1, out2);
    hist_part<<<64, 256, 0, stream>>>(idxg, partial);
    entropy_kernel<<<1, NCODE, 0, stream>>>(partial, oent);
}